// Round 5
// baseline (421.514 us; speedup 1.0000x reference)
//
#include <hip/hip_runtime.h>
#include <math.h>

#define EPS_F 1e-5f
#define NPOINTS 550   // sum_{i=1..10} 10*i
#define CIN 512

// jax.nn.softplus(z) = max(z,0) + log1p(exp(-|z|))
static __device__ __forceinline__ float softplus_f(float z) {
    return fmaxf(z, 0.0f) + log1pf(expf(-fabsf(z)));
}

static __device__ __forceinline__ float dot8(const float4 a0, const float4 a1,
                                             const float4 w0, const float4 w1) {
    float s = a0.x * w0.x;
    s = fmaf(a0.y, w0.y, s);
    s = fmaf(a0.z, w0.z, s);
    s = fmaf(a0.w, w0.w, s);
    s = fmaf(a1.x, w1.x, s);
    s = fmaf(a1.y, w1.y, s);
    s = fmaf(a1.z, w1.z, s);
    s = fmaf(a1.w, w1.w, s);
    return s;
}

// ======================= Kernel A: streaming dual-GEMV ======================
// Pure stream: per 2-row stage a wave issues 4x b128 loads (double-buffered),
// 8 dot8 FMAs, a 4-op LDS transpose + 4 shuffles, one 16B store to ws.
// grid 1024 x 256 thr, 128 rows/block, 32 rows/wave (16 stages). VGPR-lean.
__global__ __launch_bounds__(256, 4) void gemv_kernel(
    const float* __restrict__ x,
    const float* __restrict__ Wa,
    const float* __restrict__ Wb,
    float* __restrict__ ws)           // [batch][2] raw dots (pre-bias)
{
    __shared__ float part[4][4][68];  // [wave][r*2+v][lane(+pad)]

    const int tid = threadIdx.x;
    const int lane = tid & 63;
    const int wave = tid >> 6;
    const long waveRow0 = (long)blockIdx.x * 128 + wave * 32;

    const float4* Wa4 = (const float4*)Wa;
    const float4* Wb4 = (const float4*)Wb;
    const float4 wa0 = Wa4[lane], wa1 = Wa4[64 + lane];
    const float4 wb0 = Wb4[lane], wb1 = Wb4[64 + lane];

    const int g = lane >> 4;          // 0..3 -> (row = g>>1, val = g&1)
    const int k = lane & 15;

    float4 buf[2][4];
    {   // prefetch stage 0 (rows 0,1)
        const float4* xr = (const float4*)(x + waveRow0 * CIN);
        buf[0][0] = xr[lane];         // row0 cols 0..255 (1KB coalesced)
        buf[0][1] = xr[64 + lane];    // row0 cols 256..511
        buf[0][2] = xr[128 + lane];   // row1 cols 0..255
        buf[0][3] = xr[192 + lane];   // row1 cols 256..511
    }

    #pragma unroll
    for (int t = 0; t < 16; ++t) {
        const int cur = t & 1;
        if (t + 1 < 16) {             // prefetch next stage before consuming
            const float4* xn = (const float4*)(x + (waveRow0 + (t + 1) * 2) * CIN);
            buf[cur ^ 1][0] = xn[lane];
            buf[cur ^ 1][1] = xn[64 + lane];
            buf[cur ^ 1][2] = xn[128 + lane];
            buf[cur ^ 1][3] = xn[192 + lane];
        }

        const float pa0 = dot8(buf[cur][0], buf[cur][1], wa0, wa1);
        const float pb0 = dot8(buf[cur][0], buf[cur][1], wb0, wb1);
        const float pa1 = dot8(buf[cur][2], buf[cur][3], wa0, wa1);
        const float pb1 = dot8(buf[cur][2], buf[cur][3], wb0, wb1);

        // per-wave transpose reduction (wave-synchronous, no barrier)
        part[wave][0][lane] = pa0;
        part[wave][1][lane] = pb0;
        part[wave][2][lane] = pa1;
        part[wave][3][lane] = pb1;
        asm volatile("s_waitcnt lgkmcnt(0)" ::: "memory");

        const float4 q = *(const float4*)&part[wave][g][k * 4];
        float s = (q.x + q.y) + (q.z + q.w);
        s += __shfl_xor(s, 8, 64);
        s += __shfl_xor(s, 4, 64);
        s += __shfl_xor(s, 2, 64);
        s += __shfl_xor(s, 1, 64);    // 16-lane group g holds full sum

        // idx = (row*2+val) = (waveRow0 + t*2)*2 + g ; lanes 0/16/32/48 store
        if (k == 0) ws[(waveRow0 + t * 2) * 2 + g] = s;
    }
}

// ===================== Kernel B: quadrature + normalize =====================
// Thread-per-row: reads (da,db) from ws, 550 broadcast LDS table points,
// 10 independent per-threshold sums, staged coalesced float4 output.
__global__ __launch_bounds__(256, 4) void quad_kernel(
    const float* __restrict__ ws,
    const float* __restrict__ ba, const float* __restrict__ bb,
    float* __restrict__ out)
{
    __shared__ __align__(16) float2 tab[NPOINTS];  // (log2 g, log2(1-g))
    __shared__ float outb[256 * 10];

    const int tid = threadIdx.x;

    for (int p = tid; p < NPOINTS; p += 256) {
        int i = 1, off = 0;
        while (p >= off + 10 * i) { off += 10 * i; ++i; }
        const int j = p - off;
        const int n = 10 * i;
        const float thr = (float)i * 0.1f;
        const float step = (thr - 2.0f * EPS_F) / (float)(n - 1);
        const float gx = EPS_F + step * (float)j;      // matches jnp.linspace f32
        float2 e;
        e.x = log2f(gx);
        e.y = log2f(1.0f - gx);
        tab[p] = e;
    }
    __syncthreads();

    const long row = (long)blockIdx.x * 256 + tid;
    const float2 d = ((const float2*)ws)[row];         // coalesced 8B/lane
    const float za = d.x + ba[0];
    const float zb = d.y + bb[0];
    const float alpha = fminf(fmaxf(1.0f + softplus_f(za), 1.0f), 100.0f);
    const float beta  = fminf(fmaxf(1.0f + softplus_f(zb), 1.0f), 100.0f);
    const float am1 = alpha - 1.0f;
    const float bm1 = beta - 1.0f;

    // Stabilizer at the Beta mode (lbeta/dx are common positive factors and
    // cancel in the normalization; concave exponent => exp2 args <= 0).
    const float denom = am1 + bm1;
    float mode = (denom > 0.0f) ? (am1 / denom) : 0.5f;
    mode = fminf(fmaxf(mode, 1e-7f), 1.0f - 1.1920929e-7f);
    const float nM2 = -(am1 * log2f(mode) + bm1 * log2f(1.0f - mode));

    float seg[10];                    // per-threshold full quadrature sums
    int p0 = 0;
    #pragma unroll
    for (int i = 1; i <= 10; ++i) {
        const int n = 10 * i;         // even; p0 even -> float4-aligned reads
        float s2 = 0.0f;
        for (int j = 0; j < n; j += 2) {
            const float4 tq = *(const float4*)&tab[p0 + j];  // broadcast read
            const float e0 = fmaf(am1, tq.x, fmaf(bm1, tq.y, nM2));
            const float e1 = fmaf(am1, tq.z, fmaf(bm1, tq.w, nM2));
            s2 += __builtin_amdgcn_exp2f(e0) + __builtin_amdgcn_exp2f(e1);
        }
        seg[i - 1] = s2;
        p0 += n;
    }

    const float inv = 1.0f / seg[9];
    float prev = 0.0f;
    #pragma unroll
    for (int kk = 0; kk < 10; ++kk) {
        outb[tid * 10 + kk] = (seg[kk] - prev) * inv;
        prev = seg[kk];
    }
    __syncthreads();

    // coalesced block write: 2560 floats = 640 float4
    const float4* s4 = (const float4*)outb;
    float4* dst = (float4*)(out + (size_t)blockIdx.x * 2560);
    #pragma unroll
    for (int idx = tid; idx < 640; idx += 256) dst[idx] = s4[idx];
}

extern "C" void kernel_launch(void* const* d_in, const int* in_sizes, int n_in,
                              void* d_out, int out_size, void* d_ws, size_t ws_size,
                              hipStream_t stream) {
    const float* x  = (const float*)d_in[0];
    const float* Wa = (const float*)d_in[1];
    const float* ba = (const float*)d_in[2];
    const float* Wb = (const float*)d_in[3];
    const float* bb = (const float*)d_in[4];
    float* out = (float*)d_out;
    float* ws  = (float*)d_ws;       // 1 MB: [batch][2] raw dots

    const int batch = in_sizes[0] / CIN;     // 131072
    gemv_kernel<<<batch / 128, 256, 0, stream>>>(x, Wa, Wb, ws);
    quad_kernel<<<batch / 256, 256, 0, stream>>>(ws, ba, bb, out);
}